// Round 1
// 453.338 us; speedup vs baseline: 1.1463x; 1.1463x over previous
//
#include <hip/hip_runtime.h>

#define NB 65536
#define CBLK 256

typedef unsigned long long u64;
typedef __attribute__((ext_vector_type(8))) short short8;   // 8 bf16 (guide-verified typing)
typedef __attribute__((ext_vector_type(4))) float f32x4;

union FragAB { unsigned short us[8]; unsigned w[4]; short8 v; };

__device__ __forceinline__ float fast_rcp(float x){ return __builtin_amdgcn_rcpf(x); }
// fast sigmoid/tanh: v_exp + v_rcp, no fp32 div sequence
__device__ __forceinline__ float sigf(float x){ return fast_rcp(1.0f + __expf(-x)); }
__device__ __forceinline__ float tanh_fast(float x){ return 1.0f - 2.0f*fast_rcp(1.0f + __expf(2.0f*x)); }

__device__ __forceinline__ unsigned short f2bf(float f){
    union { float f; unsigned u; } x; x.f = f;
    unsigned r = x.u + 0x7FFFu + ((x.u >> 16) & 1u);   // RNE
    return (unsigned short)(r >> 16);
}
__device__ __forceinline__ float bf2f(unsigned short h){
    union { unsigned u; float f; } x; x.u = ((unsigned)h) << 16; return x.f;
}

// ============ Kernel 1: conv1+bn1+relu -> conv2+bn2+relu -> LIF1 -> LIF2 (registers!) ============
// UNCHANGED from previous round (isolating the k_lstm_mfma delta).
__global__ __launch_bounds__(CBLK)
void k_conv_lif(const float* __restrict__ x,
                const float* __restrict__ c1w, const float* __restrict__ c1b,
                const float* __restrict__ b1g, const float* __restrict__ b1b,
                const float* __restrict__ b1m, const float* __restrict__ b1v,
                const float* __restrict__ c2w, const float* __restrict__ c2b,
                const float* __restrict__ b2g, const float* __restrict__ b2b,
                const float* __restrict__ b2m, const float* __restrict__ b2v,
                u64* __restrict__ spk,
                float* __restrict__ avg)
{
    const int b = blockIdx.x * CBLK + threadIdx.x;
    const float* xr = x + (size_t)b * 360;

    float w1f[6][5], c1f[6];
    #pragma unroll
    for (int c = 0; c < 6; ++c) {
        float s = b1g[c] / sqrtf(b1v[c] + 1e-5f);
        #pragma unroll
        for (int j = 0; j < 5; ++j) w1f[c][j] = c1w[c*5+j] * s;
        c1f[c] = (c1b[c] - b1m[c]) * s + b1b[c];
    }
    float s2v[12], t2v[12];
    #pragma unroll
    for (int c = 0; c < 12; ++c) {
        float s = b2g[c] / sqrtf(b2v[c] + 1e-5f);
        s2v[c] = s;
        t2v[c] = (c2b[c] - b2m[c]) * s + b2b[c];
    }

    float m1[33], m2[33];
    #pragma unroll
    for (int k = 0; k < 33; ++k) { m1[k] = 0.f; m2[k] = 0.f; }

    float sum12[12];
    #pragma unroll
    for (int c = 0; c < 12; ++c) sum12[c] = 0.f;

    float hA[6], hB[6], hC[6];
    #pragma unroll
    for (int c = 0; c < 6; ++c) hA[c] = 0.f;

    #pragma unroll 1
    for (int ss = 0; ss < 8; ++ss) {
        float xw[52];
        #pragma unroll
        for (int e = 0; e < 13; ++e) {
            int gi = 44*ss - 4 + 4*e;
            float4 v;
            if (gi >= 0) v = *(const float4*)(xr + gi);
            else         v = make_float4(0.f, 0.f, 0.f, 0.f);
            xw[4*e+0] = v.x; xw[4*e+1] = v.y; xw[4*e+2] = v.z; xw[4*e+3] = v.w;
        }

        unsigned curlo = 0u, curhi = 0u;
        #pragma unroll
        for (int pi = 0; pi < 11; ++pi) {
            const float xv0 = xw[4*pi+2], xv1 = xw[4*pi+3], xv2 = xw[4*pi+4],
                        xv3 = xw[4*pi+5], xv4 = xw[4*pi+6], xv5 = xw[4*pi+7],
                        xv6 = xw[4*pi+8];
            #pragma unroll
            for (int c = 0; c < 6; ++c) {
                float aB = c1f[c] + w1f[c][0]*xv0 + w1f[c][1]*xv1 + w1f[c][2]*xv2
                                  + w1f[c][3]*xv3 + w1f[c][4]*xv4;
                float aC = c1f[c] + w1f[c][0]*xv2 + w1f[c][1]*xv3 + w1f[c][2]*xv4
                                  + w1f[c][3]*xv5 + w1f[c][4]*xv6;
                hB[c] = fmaxf(aB, 0.f);
                hC[c] = fmaxf(aC, 0.f);
            }
            #pragma unroll
            for (int c2 = 0; c2 < 12; ++c2) {
                float acc = 0.f;
                #pragma unroll
                for (int c1 = 0; c1 < 6; ++c1) {
                    const float* wp = c2w + c2*18 + c1*3;
                    acc += wp[0]*hA[c1] + wp[1]*hB[c1] + wp[2]*hC[c1];
                }
                float hv = fmaxf(acc*s2v[c2] + t2v[c2], 0.f);
                sum12[c2] += hv;

                const int ls = 12*pi + c2;
                const int kk = ls % 33;
                float v1 = 0.95f*m1[kk] + hv;
                float sp1 = (v1 > 0.5f) ? 1.f : 0.f;
                m1[kk] = v1 * (1.f - sp1);
                float v2 = 0.9f*m2[kk] + sp1;
                bool sp2 = (v2 > 0.6f);
                m2[kk] = sp2 ? 0.f : v2;
                if (sp2) { if (kk < 32) curlo |= (1u << kk); else curhi |= 1u; }
                if (kk == 32) {
                    spk[(size_t)(4*ss + ls/33)*NB + b] = ((u64)curhi << 32) | (u64)curlo;
                    curlo = 0u; curhi = 0u;
                }
            }
            #pragma unroll
            for (int c = 0; c < 6; ++c) hA[c] = hC[c];
        }
    }

    {
        float xw2[13];
        float4 a0 = *(const float4*)(xr + 348);
        float4 a1 = *(const float4*)(xr + 352);
        float4 a2 = *(const float4*)(xr + 356);
        xw2[0]=a0.x; xw2[1]=a0.y; xw2[2]=a0.z; xw2[3]=a0.w;
        xw2[4]=a1.x; xw2[5]=a1.y; xw2[6]=a1.z; xw2[7]=a1.w;
        xw2[8]=a2.x; xw2[9]=a2.y; xw2[10]=a2.z; xw2[11]=a2.w;
        xw2[12]=0.f;
        #pragma unroll
        for (int pt = 0; pt < 2; ++pt) {
            const float xv0 = xw2[2+4*pt], xv1 = xw2[3+4*pt], xv2 = xw2[4+4*pt],
                        xv3 = xw2[5+4*pt], xv4 = xw2[6+4*pt], xv5 = xw2[7+4*pt],
                        xv6 = xw2[8+4*pt];
            #pragma unroll
            for (int c = 0; c < 6; ++c) {
                float aB = c1f[c] + w1f[c][0]*xv0 + w1f[c][1]*xv1 + w1f[c][2]*xv2
                                  + w1f[c][3]*xv3 + w1f[c][4]*xv4;
                float aC = c1f[c] + w1f[c][0]*xv2 + w1f[c][1]*xv3 + w1f[c][2]*xv4
                                  + w1f[c][3]*xv5 + w1f[c][4]*xv6;
                hB[c] = fmaxf(aB, 0.f);
                hC[c] = fmaxf(aC, 0.f);
            }
            #pragma unroll
            for (int c2 = 0; c2 < 12; ++c2) {
                float acc = 0.f;
                #pragma unroll
                for (int c1 = 0; c1 < 6; ++c1) {
                    const float* wp = c2w + c2*18 + c1*3;
                    acc += wp[0]*hA[c1] + wp[1]*hB[c1] + wp[2]*hC[c1];
                }
                sum12[c2] += fmaxf(acc*s2v[c2] + t2v[c2], 0.f);
            }
            #pragma unroll
            for (int c = 0; c < 6; ++c) hA[c] = hC[c];
        }
    }
    #pragma unroll
    for (int c = 0; c < 12; ++c) avg[(size_t)c*NB + b] = sum12[c] / 90.0f;
}

// ============ Kernel 2: MFMA LSTM (split-bf16) + heads ============
// h exchange via swizzled LDS rows (128B/sample):
//   bytes   0.. 47 : h_hi bf16 at position p = 6*(u&3) + (u>>2)   (16B blocks 0..2)
//   bytes  48.. 63 : zero pad (block 3)  -> k-slots 24..31 read 0
//   bytes  64..111 : h_lo bf16, same positions                    (blocks 4..6)
//   bytes 112..127 : zero pad (block 7)
// 16B blocks XOR-swizzled by ((n16&7)<<4): ds_write_b32 spread over 32 banks (2-way max);
// unit permutation absorbed in the one-time Whh fragment k-indexing (u(s)=4*(s%6)+s/6).
// Bias folded into the 3rd Wih MFMA at k=33(hi)/k=34(lo) vs constant-1.0 B slots.
__global__ __launch_bounds__(256, 2)
void k_lstm_mfma(const u64* __restrict__ spk,
                 const float* __restrict__ avg,
                 const float* __restrict__ wih, const float* __restrict__ whh,
                 const float* __restrict__ bih, const float* __restrict__ bhh,
                 const float* __restrict__ rw1, const float* __restrict__ rb1,
                 const float* __restrict__ rw2, const float* __restrict__ rb2,
                 const float* __restrict__ fw,  const float* __restrict__ fb,
                 const float* __restrict__ cw1, const float* __restrict__ cb1,
                 const float* __restrict__ cw2, const float* __restrict__ cb2,
                 float* __restrict__ out)
{
    __shared__ __align__(128) unsigned short hx[4][16][64];   // 8 KB

    const int tid  = threadIdx.x;
    const int lane = tid & 63;
    const int wv   = __builtin_amdgcn_readfirstlane(tid >> 6);
    const int q    = lane >> 4;       // k-slice group (A and B) / row-quad (C)
    const int n16  = lane & 15;       // sample col (B/C) ; row-in-tile (A)
    const int sample = blockIdx.x * 64 + wv * 16 + n16;
    const int q8 = q * 8;

    // zero this wave's hx region (h(t=-1)=0 and the pad zeros; pads are never written after)
    {
        unsigned* zp = (unsigned*)&hx[wv][0][0];
        #pragma unroll
        for (int i = 0; i < 8; ++i) zp[lane + 64*i] = 0u;
    }

    const int swz = (n16 & 7) << 4;
    char* rowb = (char*)&hx[wv][n16][0];
    unsigned* whiP[3]; unsigned* wloP[3];
    #pragma unroll
    for (int j = 0; j < 3; ++j) {
        whiP[j] = (unsigned*)(rowb + (( 0 + 12*q + 4*j) ^ swz));
        wloP[j] = (unsigned*)(rowb + ((64 + 12*q + 4*j) ^ swz));
    }
    const short8* rdhi = (const short8*)(rowb + (( 0 + 16*q) ^ swz));
    const short8* rdlo = (const short8*)(rowb + ((64 + 16*q) ^ swz));

    // ---- load A fragments (weights), one-time ----
    short8 WihHi[6][2], WihLo[6], WhhHi[6], WhhLo[6];
    #pragma unroll
    for (int m = 0; m < 6; ++m) {
        const int rowA = 16*m + n16;           // A-layout: row = lane&15
        const int u    = rowA >> 2;
        const int gt   = rowA & 3;
        const float* wr = wih + (gt*24 + u)*33;
        FragAB fh, fl;
        #pragma unroll
        for (int j = 0; j < 8; ++j) {
            float v = wr[q8 + j];              // k = q*8+j, all < 32 valid
            unsigned short h = f2bf(v);
            fh.us[j] = h;
            fl.us[j] = f2bf(v - bf2f(h));
        }
        WihHi[m][0] = fh.v; WihLo[m] = fl.v;

        // 2nd Wih k-tile: k=32 spike bit + row bias split at k=33 (hi) / k=34 (lo)
        FragAB f1z;
        #pragma unroll
        for (int j = 0; j < 8; ++j) f1z.us[j] = 0;
        if (q == 0) {
            f1z.us[0] = f2bf(wr[32]);
            float bs = bih[gt*24 + u] + bhh[gt*24 + u];
            unsigned short bh = f2bf(bs);
            f1z.us[1] = bh;
            f1z.us[2] = f2bf(bs - bf2f(bh));
        }
        WihHi[m][1] = f1z.v;

        // Whh with permuted k: LDS position s holds h of unit 4*(s%6)+s/6
        const float* hr = whh + (gt*24 + u)*24;
        FragAB gh, gl;
        #pragma unroll
        for (int j = 0; j < 8; ++j) {
            int s = q8 + j;
            float v = 0.f;
            if (s < 24) v = hr[4*(s % 6) + (s / 6)];
            unsigned short h = f2bf(v);
            gh.us[j] = h;
            gl.us[j] = (s < 24) ? f2bf(v - bf2f(h)) : (unsigned short)0;
        }
        WhhHi[m] = gh.v; WhhLo[m] = gl.v;
    }

    float cst[6], hreg[6];
    #pragma unroll
    for (int m = 0; m < 6; ++m) { cst[m] = 0.f; hreg[m] = 0.f; }

    const u64* sp = spk + sample;
    u64 wcur = sp[0];

    __asm__ volatile("s_waitcnt lgkmcnt(0)" ::: "memory");   // hx zero visible to own wave

    #pragma unroll 1
    for (int t = 0; t < 32; ++t) {
        // B fragments for h (state t-1; zeros at t=0 via init)
        short8 BhHi = *rdhi;
        short8 BhLo = *rdlo;

        // B fragments for spikes (exact bf16 0/1)
        const unsigned lo32 = (unsigned)wcur;
        const unsigned hi32 = (unsigned)(wcur >> 32);
        FragAB bs0;
        {
            const unsigned byt = (lo32 >> q8) & 0xFFu;
            #pragma unroll
            for (int p = 0; p < 4; ++p) {
                unsigned e0 = (byt >> (2*p)) & 1u;
                unsigned e1 = (byt >> (2*p+1)) & 1u;
                bs0.w[p] = (e0 ? 0x3F80u : 0u) | (e1 ? 0x3F800000u : 0u);
            }
        }
        // k=32 spike + constant 1.0 at k=33/34 (bias slots). Nonzero on q!=0 lanes is
        // harmless: matching A slots there are 0.
        FragAB bs1;
        bs1.w[0] = 0x3F800000u | ((hi32 & 1u) ? 0x3F80u : 0u);
        bs1.w[1] = 0x00003F80u;
        bs1.w[2] = 0u; bs1.w[3] = 0u;

        // prefetch next spike word early
        u64 wnext = 0;
        if (t < 31) wnext = sp[(size_t)(t+1)*NB];

        // gates = (bias via k33/34) + Wih*spk + Whh*h  (split-bf16)
        f32x4 acc[6];
        #pragma unroll
        for (int m = 0; m < 6; ++m) {
            f32x4 a = {0.f, 0.f, 0.f, 0.f};
            a = __builtin_amdgcn_mfma_f32_16x16x32_bf16(WihHi[m][0], bs0.v, a, 0, 0, 0);
            a = __builtin_amdgcn_mfma_f32_16x16x32_bf16(WihLo[m],    bs0.v, a, 0, 0, 0);
            a = __builtin_amdgcn_mfma_f32_16x16x32_bf16(WihHi[m][1], bs1.v, a, 0, 0, 0);
            a = __builtin_amdgcn_mfma_f32_16x16x32_bf16(WhhHi[m],    BhHi,  a, 0, 0, 0);
            a = __builtin_amdgcn_mfma_f32_16x16x32_bf16(WhhLo[m],    BhHi,  a, 0, 0, 0);
            a = __builtin_amdgcn_mfma_f32_16x16x32_bf16(WhhHi[m],    BhLo,  a, 0, 0, 0);
            acc[m] = a;
        }

        // epilogue: lane-local LSTM cell for units 4m+q of its sample
        #pragma unroll
        for (int m = 0; m < 6; ++m) {
            float ii = sigf(acc[m][0]);
            float ff = sigf(acc[m][1]);
            float gg = tanh_fast(acc[m][2]);
            float oo = sigf(acc[m][3]);
            float cn = ff*cst[m] + ii*gg;
            cst[m] = cn;
            hreg[m] = oo * tanh_fast(cn);
        }
        // pack pairs (m=2j, 2j+1) -> positions 6q+2j, 6q+2j+1; trunc-hi + RNE-lo split
        #pragma unroll
        for (int j = 0; j < 3; ++j) {
            union { float f; unsigned u; } a0, a1;
            a0.f = hreg[2*j]; a1.f = hreg[2*j+1];
            unsigned hiw = (a0.u >> 16) | (a1.u & 0xFFFF0000u);
            union { unsigned u; float f; } t0, t1;
            t0.u = a0.u & 0xFFFF0000u; t1.u = a1.u & 0xFFFF0000u;
            unsigned low = (unsigned)f2bf(a0.f - t0.f) | ((unsigned)f2bf(a1.f - t1.f) << 16);
            *whiP[j] = hiw;
            *wloP[j] = low;
        }
        __asm__ volatile("s_waitcnt lgkmcnt(0)" ::: "memory");  // intra-wave ds RAW
        wcur = wnext;
    }

    // ---------- head: all 64 lanes, 4 lanes per sample, shfl_xor(16/32) butterflies ----------
    float av3[3];
    #pragma unroll
    for (int i = 0; i < 3; ++i) av3[i] = avg[(size_t)(3*q + i)*NB + sample];

    float f1v[12];
    #pragma unroll
    for (int r = 0; r < 12; ++r) {
        float a = 0.f;
        #pragma unroll
        for (int m = 0; m < 6; ++m) a += rw1[r*36 + 4*m + q] * hreg[m];
        #pragma unroll
        for (int i = 0; i < 3; ++i) a += rw1[r*36 + 24 + 3*q + i] * av3[i];
        a += __shfl_xor(a, 16);
        a += __shfl_xor(a, 32);
        f1v[r] = fmaxf(a + rb1[r], 0.f);
    }
    float z0 = rb2[0], z1 = rb2[1];
    #pragma unroll
    for (int r = 0; r < 12; ++r) { z0 += rw2[r]*f1v[r]; z1 += rw2[12+r]*f1v[r]; }
    float mz = fmaxf(z0, z1);
    float e0 = 0.7f*__expf(z0 - mz), e1 = 0.3f*__expf(z1 - mz);
    float alpha = e0 * fast_rcp(e0 + e1);

    float ha[6], sa3[3];
    #pragma unroll
    for (int m = 0; m < 6; ++m) ha[m] = hreg[m]*alpha;
    #pragma unroll
    for (int i = 0; i < 3; ++i) sa3[i] = av3[i]*(1.f - alpha);

    float fuv[24];
    #pragma unroll
    for (int r = 0; r < 24; ++r) {
        float a = 0.f;
        #pragma unroll
        for (int m = 0; m < 6; ++m) a += fw[r*36 + 4*m + q] * ha[m];
        #pragma unroll
        for (int i = 0; i < 3; ++i) a += fw[r*36 + 24 + 3*q + i] * sa3[i];
        a += __shfl_xor(a, 16);
        a += __shfl_xor(a, 32);
        fuv[r] = fmaxf(a + fb[r], 0.f);
    }
    // classifier layer 1: lane q owns rows 3q..3q+2 (static register indexing only)
    float c1r[3];
    #pragma unroll
    for (int k = 0; k < 3; ++k) {
        const int r = 3*q + k;
        float a = cb1[r];
        #pragma unroll
        for (int u2 = 0; u2 < 24; ++u2) a += cw1[r*24 + u2] * fuv[u2];
        c1r[k] = fmaxf(a, 0.f);
    }
    // output layer: butterfly partial sums over the distributed c1 rows
    #pragma unroll
    for (int o = 0; o < 5; ++o) {
        float a = 0.f;
        #pragma unroll
        for (int k = 0; k < 3; ++k) a += cw2[o*12 + 3*q + k] * c1r[k];
        a += __shfl_xor(a, 16);
        a += __shfl_xor(a, 32);
        if (q == 0) out[(size_t)sample*5 + o] = a + cb2[o];
    }
}

extern "C" void kernel_launch(void* const* d_in, const int* in_sizes, int n_in,
                              void* d_out, int out_size, void* d_ws, size_t ws_size,
                              hipStream_t stream) {
    const float* x    = (const float*)d_in[0];
    const float* c1w  = (const float*)d_in[1];
    const float* c1b  = (const float*)d_in[2];
    const float* b1g  = (const float*)d_in[3];
    const float* b1b  = (const float*)d_in[4];
    const float* b1m  = (const float*)d_in[5];
    const float* b1v  = (const float*)d_in[6];
    const float* c2w  = (const float*)d_in[7];
    const float* c2b  = (const float*)d_in[8];
    const float* b2g  = (const float*)d_in[9];
    const float* b2b  = (const float*)d_in[10];
    const float* b2m  = (const float*)d_in[11];
    const float* b2v  = (const float*)d_in[12];
    const float* wih  = (const float*)d_in[13];
    const float* whh  = (const float*)d_in[14];
    const float* bih  = (const float*)d_in[15];
    const float* bhh  = (const float*)d_in[16];
    const float* rw1  = (const float*)d_in[17];
    const float* rb1  = (const float*)d_in[18];
    const float* rw2  = (const float*)d_in[19];
    const float* rb2  = (const float*)d_in[20];
    const float* fw   = (const float*)d_in[21];
    const float* fb   = (const float*)d_in[22];
    const float* cw1  = (const float*)d_in[23];
    const float* cb1  = (const float*)d_in[24];
    const float* cw2  = (const float*)d_in[25];
    const float* cb2  = (const float*)d_in[26];
    float* out = (float*)d_out;

    u64* spk  = (u64*)d_ws;                                            // 16.78 MB
    float* avg = (float*)((char*)d_ws + (size_t)32*NB*sizeof(u64));    // 3.15 MB

    k_conv_lif<<<dim3(NB/CBLK), dim3(CBLK), 0, stream>>>(x, c1w, c1b, b1g, b1b, b1m, b1v,
                                                         c2w, c2b, b2g, b2b, b2m, b2v, spk, avg);
    k_lstm_mfma<<<dim3(NB/64), dim3(256), 0, stream>>>(spk, avg, wih, whh, bih, bhh,
                                                       rw1, rb1, rw2, rb2, fw, fb,
                                                       cw1, cb1, cw2, cb2, out);
}

// Round 4
// 452.086 us; speedup vs baseline: 1.1495x; 1.0028x over previous
//
#include <hip/hip_runtime.h>

#define NB 65536
#define CBLK 256

typedef unsigned long long u64;
typedef __attribute__((ext_vector_type(8))) short short8;   // 8 bf16 (guide-verified typing)
typedef __attribute__((ext_vector_type(4))) float f32x4;

union FragAB { unsigned short us[8]; unsigned w[4]; short8 v; };

__device__ __forceinline__ float fast_rcp(float x){ return __builtin_amdgcn_rcpf(x); }
__device__ __forceinline__ float sigf(float x){ return fast_rcp(1.0f + __expf(-x)); }
__device__ __forceinline__ float tanh_fast(float x){ return 1.0f - 2.0f*fast_rcp(1.0f + __expf(2.0f*x)); }

__device__ __forceinline__ unsigned short f2bf(float f){
    union { float f; unsigned u; } x; x.f = f;
    unsigned r = x.u + 0x7FFFu + ((x.u >> 16) & 1u);   // RNE
    return (unsigned short)(r >> 16);
}
__device__ __forceinline__ float bf2f(unsigned short h){
    union { unsigned u; float f; } x; x.u = ((unsigned)h) << 16; return x.f;
}

// ============ Kernel 1: conv1+bn1+relu -> conv2+bn2+relu -> LIF1 -> LIF2 ============
// Numerics BIT-IDENTICAL to the round-0/1 version (LIF thresholds are rounding-critical).
// Only change: ping-pong double-buffered x-window with one-superstep-ahead prefetch.
// Grid is 1 wave/SIMD (one thread per sample), so ILP is the only latency hiding.
// Macros (not functions) keep the window buffers in registers (no pointer escapes).

#define LOADW(XW, SS) do {                                              \
    _Pragma("unroll")                                                   \
    for (int e = 0; e < 13; ++e) {                                      \
        float4 v = *(const float4*)(xr + (44*(SS) - 4 + 4*e));          \
        XW[4*e+0] = v.x; XW[4*e+1] = v.y;                               \
        XW[4*e+2] = v.z; XW[4*e+3] = v.w;                               \
    }                                                                   \
} while (0)

#define SUPERSTEP(XW, SS) do {                                          \
    unsigned curlo = 0u, curhi = 0u;                                    \
    _Pragma("unroll")                                                   \
    for (int pi = 0; pi < 11; ++pi) {                                   \
        const float xv0 = XW[4*pi+2], xv1 = XW[4*pi+3], xv2 = XW[4*pi+4], \
                    xv3 = XW[4*pi+5], xv4 = XW[4*pi+6], xv5 = XW[4*pi+7], \
                    xv6 = XW[4*pi+8];                                   \
        _Pragma("unroll")                                               \
        for (int c = 0; c < 6; ++c) {                                   \
            float aB = c1f[c] + w1f[c][0]*xv0 + w1f[c][1]*xv1 + w1f[c][2]*xv2 \
                              + w1f[c][3]*xv3 + w1f[c][4]*xv4;          \
            float aC = c1f[c] + w1f[c][0]*xv2 + w1f[c][1]*xv3 + w1f[c][2]*xv4 \
                              + w1f[c][3]*xv5 + w1f[c][4]*xv6;          \
            hB[c] = fmaxf(aB, 0.f);                                     \
            hC[c] = fmaxf(aC, 0.f);                                     \
        }                                                               \
        _Pragma("unroll")                                               \
        for (int c2 = 0; c2 < 12; ++c2) {                               \
            float acc = 0.f;                                            \
            _Pragma("unroll")                                           \
            for (int c1 = 0; c1 < 6; ++c1) {                            \
                const float* wp = c2w + c2*18 + c1*3;                   \
                acc += wp[0]*hA[c1] + wp[1]*hB[c1] + wp[2]*hC[c1];      \
            }                                                           \
            float hv = fmaxf(acc*s2v[c2] + t2v[c2], 0.f);               \
            sum12[c2] += hv;                                            \
            const int ls = 12*pi + c2;                                  \
            const int kk = ls % 33;                                     \
            float v1 = 0.95f*m1[kk] + hv;                               \
            float sp1 = (v1 > 0.5f) ? 1.f : 0.f;                        \
            m1[kk] = v1 * (1.f - sp1);                                  \
            float v2 = 0.9f*m2[kk] + sp1;                               \
            bool sp2 = (v2 > 0.6f);                                     \
            m2[kk] = sp2 ? 0.f : v2;                                    \
            if (sp2) { if (kk < 32) curlo |= (1u << kk); else curhi |= 1u; } \
            if (kk == 32) {                                             \
                spk[(size_t)(4*(SS) + ls/33)*NB + b] = ((u64)curhi << 32) | (u64)curlo; \
                curlo = 0u; curhi = 0u;                                 \
            }                                                           \
        }                                                               \
        _Pragma("unroll")                                               \
        for (int c = 0; c < 6; ++c) hA[c] = hC[c];                      \
    }                                                                   \
} while (0)

__global__ __launch_bounds__(CBLK)
void k_conv_lif(const float* __restrict__ x,
                const float* __restrict__ c1w, const float* __restrict__ c1b,
                const float* __restrict__ b1g, const float* __restrict__ b1b,
                const float* __restrict__ b1m, const float* __restrict__ b1v,
                const float* __restrict__ c2w, const float* __restrict__ c2b,
                const float* __restrict__ b2g, const float* __restrict__ b2b,
                const float* __restrict__ b2m, const float* __restrict__ b2v,
                u64* __restrict__ spk,
                float* __restrict__ avg)
{
    const int b = blockIdx.x * CBLK + threadIdx.x;
    const float* xr = x + (size_t)b * 360;

    float w1f[6][5], c1f[6];
    #pragma unroll
    for (int c = 0; c < 6; ++c) {
        float s = b1g[c] / sqrtf(b1v[c] + 1e-5f);
        #pragma unroll
        for (int j = 0; j < 5; ++j) w1f[c][j] = c1w[c*5+j] * s;
        c1f[c] = (c1b[c] - b1m[c]) * s + b1b[c];
    }
    float s2v[12], t2v[12];
    #pragma unroll
    for (int c = 0; c < 12; ++c) {
        float s = b2g[c] / sqrtf(b2v[c] + 1e-5f);
        s2v[c] = s;
        t2v[c] = (c2b[c] - b2m[c]) * s + b2b[c];
    }

    float m1[33], m2[33];
    #pragma unroll
    for (int k = 0; k < 33; ++k) { m1[k] = 0.f; m2[k] = 0.f; }

    float sum12[12];
    #pragma unroll
    for (int c = 0; c < 12; ++c) sum12[c] = 0.f;

    float hA[6], hB[6], hC[6];
    #pragma unroll
    for (int c = 0; c < 6; ++c) hA[c] = 0.f;

    // windows: ping-pong double buffer, prefetch one superstep ahead
    float xwA[52], xwB[52];
    {   // ss = 0 window: e=0 is the left-pad (gi = -4 < 0)
        xwA[0] = 0.f; xwA[1] = 0.f; xwA[2] = 0.f; xwA[3] = 0.f;
        #pragma unroll
        for (int e = 1; e < 13; ++e) {
            float4 v = *(const float4*)(xr + (4*e - 4));
            xwA[4*e+0] = v.x; xwA[4*e+1] = v.y; xwA[4*e+2] = v.z; xwA[4*e+3] = v.w;
        }
    }

    #pragma unroll 1
    for (int ss = 0; ss < 8; ss += 2) {
        LOADW(xwB, ss + 1);              // prefetch next window before computing this one
        SUPERSTEP(xwA, ss);
        if (ss + 2 < 8) LOADW(xwA, ss + 2);
        SUPERSTEP(xwB, ss + 1);
    }

    // tail positions 88, 89 (feed avg only) — unchanged
    {
        float xw2[13];
        float4 a0 = *(const float4*)(xr + 348);
        float4 a1 = *(const float4*)(xr + 352);
        float4 a2 = *(const float4*)(xr + 356);
        xw2[0]=a0.x; xw2[1]=a0.y; xw2[2]=a0.z; xw2[3]=a0.w;
        xw2[4]=a1.x; xw2[5]=a1.y; xw2[6]=a1.z; xw2[7]=a1.w;
        xw2[8]=a2.x; xw2[9]=a2.y; xw2[10]=a2.z; xw2[11]=a2.w;
        xw2[12]=0.f;
        #pragma unroll
        for (int pt = 0; pt < 2; ++pt) {
            const float xv0 = xw2[2+4*pt], xv1 = xw2[3+4*pt], xv2 = xw2[4+4*pt],
                        xv3 = xw2[5+4*pt], xv4 = xw2[6+4*pt], xv5 = xw2[7+4*pt],
                        xv6 = xw2[8+4*pt];
            #pragma unroll
            for (int c = 0; c < 6; ++c) {
                float aB = c1f[c] + w1f[c][0]*xv0 + w1f[c][1]*xv1 + w1f[c][2]*xv2
                                  + w1f[c][3]*xv3 + w1f[c][4]*xv4;
                float aC = c1f[c] + w1f[c][0]*xv2 + w1f[c][1]*xv3 + w1f[c][2]*xv4
                                  + w1f[c][3]*xv5 + w1f[c][4]*xv6;
                hB[c] = fmaxf(aB, 0.f);
                hC[c] = fmaxf(aC, 0.f);
            }
            #pragma unroll
            for (int c2 = 0; c2 < 12; ++c2) {
                float acc = 0.f;
                #pragma unroll
                for (int c1 = 0; c1 < 6; ++c1) {
                    const float* wp = c2w + c2*18 + c1*3;
                    acc += wp[0]*hA[c1] + wp[1]*hB[c1] + wp[2]*hC[c1];
                }
                sum12[c2] += fmaxf(acc*s2v[c2] + t2v[c2], 0.f);
            }
            #pragma unroll
            for (int c = 0; c < 6; ++c) hA[c] = hC[c];
        }
    }
    #pragma unroll
    for (int c = 0; c < 12; ++c) avg[(size_t)c*NB + b] = sum12[c] / 90.0f;
}

// ============ Kernel 2: MFMA LSTM (split-bf16) + heads — ZERO LDS ============
// Same as round 3 EXCEPT __launch_bounds__(256, 2): round 3's (256,4) capped VGPRs at
// 128 and forced scratch spills into the MFMA chain (634 us + timing-dependent
// corruption). (256,2) gives a 256-VGPR budget (~180 needed, no spills) — the setting
// round 1 proved post-timing-stable.
// Whh k-slot layout: slot 8q'+j <-> unit 4j+q' (j<6; slots 6,7 zero pads), so each
// lane's B-slice (k=8q..8q+7) is exactly its own six hreg values. No LDS, no fences.
__global__ __launch_bounds__(256, 2)
void k_lstm_mfma(const u64* __restrict__ spk,
                 const float* __restrict__ avg,
                 const float* __restrict__ wih, const float* __restrict__ whh,
                 const float* __restrict__ bih, const float* __restrict__ bhh,
                 const float* __restrict__ rw1, const float* __restrict__ rb1,
                 const float* __restrict__ rw2, const float* __restrict__ rb2,
                 const float* __restrict__ fw,  const float* __restrict__ fb,
                 const float* __restrict__ cw1, const float* __restrict__ cb1,
                 const float* __restrict__ cw2, const float* __restrict__ cb2,
                 float* __restrict__ out)
{
    const int tid  = threadIdx.x;
    const int lane = tid & 63;
    const int wv   = __builtin_amdgcn_readfirstlane(tid >> 6);
    const int q    = lane >> 4;       // k-slice group (A and B) / row-quad (C)
    const int n16  = lane & 15;       // sample col (B/C) ; row-in-tile (A)
    const int sample = blockIdx.x * 64 + wv * 16 + n16;
    const int q8 = q * 8;

    // ---- load A fragments (weights), one-time ----
    short8 WihHi[6][2], WihLo[6], WhhHi[6], WhhLo[6];
    #pragma unroll
    for (int m = 0; m < 6; ++m) {
        const int rowA = 16*m + n16;           // A-layout: row = lane&15
        const int u    = rowA >> 2;
        const int gt   = rowA & 3;
        const float* wr = wih + (gt*24 + u)*33;
        FragAB fh, fl;
        #pragma unroll
        for (int j = 0; j < 8; ++j) {
            float v = wr[q8 + j];              // k = q*8+j, all < 32 valid
            unsigned short h = f2bf(v);
            fh.us[j] = h;
            fl.us[j] = f2bf(v - bf2f(h));
        }
        WihHi[m][0] = fh.v; WihLo[m] = fl.v;

        // 2nd Wih k-tile: k=32 spike bit + row bias split at k=33 (hi) / k=34 (lo)
        FragAB f1z;
        #pragma unroll
        for (int j = 0; j < 8; ++j) f1z.us[j] = 0;
        if (q == 0) {
            f1z.us[0] = f2bf(wr[32]);
            float bs = bih[gt*24 + u] + bhh[gt*24 + u];
            unsigned short bh = f2bf(bs);
            f1z.us[1] = bh;
            f1z.us[2] = f2bf(bs - bf2f(bh));
        }
        WihHi[m][1] = f1z.v;

        // Whh A-fragment: k-slot s = 8q+j holds column for unit 4j+q (j<6), 0 for j=6,7
        const float* hr = whh + (gt*24 + u)*24;
        FragAB gh, gl;
        #pragma unroll
        for (int j = 0; j < 8; ++j) {
            float v = (j < 6) ? hr[4*j + q] : 0.f;
            unsigned short h = f2bf(v);
            gh.us[j] = (j < 6) ? h : (unsigned short)0;
            gl.us[j] = (j < 6) ? f2bf(v - bf2f(h)) : (unsigned short)0;
        }
        WhhHi[m] = gh.v; WhhLo[m] = gl.v;
    }

    float cst[6], hreg[6];
    #pragma unroll
    for (int m = 0; m < 6; ++m) { cst[m] = 0.f; hreg[m] = 0.f; }

    const u64* sp = spk + sample;
    u64 wcur = sp[0];

    #pragma unroll 1
    for (int t = 0; t < 32; ++t) {
        // B fragments for h(t-1): built from THIS lane's hreg (zeros at t=0).
        // hi = truncated top-16 bits, lo = RNE(residual)
        FragAB BH, BL;
        {
            union { float f; unsigned u; } hu[6];
            #pragma unroll
            for (int m = 0; m < 6; ++m) hu[m].f = hreg[m];
            #pragma unroll
            for (int jp = 0; jp < 3; ++jp) {
                unsigned u0 = hu[2*jp].u, u1 = hu[2*jp+1].u;
                BH.w[jp] = (u0 >> 16) | (u1 & 0xFFFF0000u);
                union { unsigned u; float f; } t0, t1;
                t0.u = u0 & 0xFFFF0000u; t1.u = u1 & 0xFFFF0000u;
                BL.w[jp] = (unsigned)f2bf(hu[2*jp].f - t0.f)
                         | ((unsigned)f2bf(hu[2*jp+1].f - t1.f) << 16);
            }
            BH.w[3] = 0u; BL.w[3] = 0u;
        }

        // B fragments for spikes (exact bf16 0/1)
        const unsigned lo32 = (unsigned)wcur;
        const unsigned hi32 = (unsigned)(wcur >> 32);
        FragAB bs0;
        {
            const unsigned byt = (lo32 >> q8) & 0xFFu;
            #pragma unroll
            for (int p = 0; p < 4; ++p) {
                unsigned e0 = (byt >> (2*p)) & 1u;
                unsigned e1 = (byt >> (2*p+1)) & 1u;
                bs0.w[p] = (e0 ? 0x3F80u : 0u) | (e1 ? 0x3F800000u : 0u);
            }
        }
        // k=32 spike + constant 1.0 at k=33/34 (bias slots); q!=0 lanes' extras hit A-zeros
        FragAB bs1;
        bs1.w[0] = 0x3F800000u | ((hi32 & 1u) ? 0x3F80u : 0u);
        bs1.w[1] = 0x00003F80u;
        bs1.w[2] = 0u; bs1.w[3] = 0u;

        // prefetch next spike word early
        u64 wnext = 0;
        if (t < 31) wnext = sp[(size_t)(t+1)*NB];

        // gates = (bias via k33/34) + Wih*spk + Whh*h  (split-bf16)
        f32x4 acc[6];
        #pragma unroll
        for (int m = 0; m < 6; ++m) {
            f32x4 a = {0.f, 0.f, 0.f, 0.f};
            a = __builtin_amdgcn_mfma_f32_16x16x32_bf16(WihHi[m][0], bs0.v, a, 0, 0, 0);
            a = __builtin_amdgcn_mfma_f32_16x16x32_bf16(WihLo[m],    bs0.v, a, 0, 0, 0);
            a = __builtin_amdgcn_mfma_f32_16x16x32_bf16(WihHi[m][1], bs1.v, a, 0, 0, 0);
            a = __builtin_amdgcn_mfma_f32_16x16x32_bf16(WhhHi[m],    BH.v,  a, 0, 0, 0);
            a = __builtin_amdgcn_mfma_f32_16x16x32_bf16(WhhLo[m],    BH.v,  a, 0, 0, 0);
            a = __builtin_amdgcn_mfma_f32_16x16x32_bf16(WhhHi[m],    BL.v,  a, 0, 0, 0);
            acc[m] = a;
        }

        // epilogue: lane-local LSTM cell for units 4m+q of its sample
        #pragma unroll
        for (int m = 0; m < 6; ++m) {
            float ii = sigf(acc[m][0]);
            float ff = sigf(acc[m][1]);
            float gg = tanh_fast(acc[m][2]);
            float oo = sigf(acc[m][3]);
            float cn = ff*cst[m] + ii*gg;
            cst[m] = cn;
            hreg[m] = oo * tanh_fast(cn);
        }
        wcur = wnext;
    }

    // ---------- head: all 64 lanes, 4 lanes per sample, shfl_xor(16/32) butterflies ----------
    float av3[3];
    #pragma unroll
    for (int i = 0; i < 3; ++i) av3[i] = avg[(size_t)(3*q + i)*NB + sample];

    float f1v[12];
    #pragma unroll
    for (int r = 0; r < 12; ++r) {
        float a = 0.f;
        #pragma unroll
        for (int m = 0; m < 6; ++m) a += rw1[r*36 + 4*m + q] * hreg[m];
        #pragma unroll
        for (int i = 0; i < 3; ++i) a += rw1[r*36 + 24 + 3*q + i] * av3[i];
        a += __shfl_xor(a, 16);
        a += __shfl_xor(a, 32);
        f1v[r] = fmaxf(a + rb1[r], 0.f);
    }
    float z0 = rb2[0], z1 = rb2[1];
    #pragma unroll
    for (int r = 0; r < 12; ++r) { z0 += rw2[r]*f1v[r]; z1 += rw2[12+r]*f1v[r]; }
    float mz = fmaxf(z0, z1);
    float e0 = 0.7f*__expf(z0 - mz), e1 = 0.3f*__expf(z1 - mz);
    float alpha = e0 * fast_rcp(e0 + e1);

    float ha[6], sa3[3];
    #pragma unroll
    for (int m = 0; m < 6; ++m) ha[m] = hreg[m]*alpha;
    #pragma unroll
    for (int i = 0; i < 3; ++i) sa3[i] = av3[i]*(1.f - alpha);

    float fuv[24];
    #pragma unroll
    for (int r = 0; r < 24; ++r) {
        float a = 0.f;
        #pragma unroll
        for (int m = 0; m < 6; ++m) a += fw[r*36 + 4*m + q] * ha[m];
        #pragma unroll
        for (int i = 0; i < 3; ++i) a += fw[r*36 + 24 + 3*q + i] * sa3[i];
        a += __shfl_xor(a, 16);
        a += __shfl_xor(a, 32);
        fuv[r] = fmaxf(a + fb[r], 0.f);
    }
    // classifier layer 1: lane q owns rows 3q..3q+2 (static register indexing only)
    float c1r[3];
    #pragma unroll
    for (int k = 0; k < 3; ++k) {
        const int r = 3*q + k;
        float a = cb1[r];
        #pragma unroll
        for (int u2 = 0; u2 < 24; ++u2) a += cw1[r*24 + u2] * fuv[u2];
        c1r[k] = fmaxf(a, 0.f);
    }
    // output layer: butterfly partial sums over the distributed c1 rows
    #pragma unroll
    for (int o = 0; o < 5; ++o) {
        float a = 0.f;
        #pragma unroll
        for (int k = 0; k < 3; ++k) a += cw2[o*12 + 3*q + k] * c1r[k];
        a += __shfl_xor(a, 16);
        a += __shfl_xor(a, 32);
        if (q == 0) out[(size_t)sample*5 + o] = a + cb2[o];
    }
}

extern "C" void kernel_launch(void* const* d_in, const int* in_sizes, int n_in,
                              void* d_out, int out_size, void* d_ws, size_t ws_size,
                              hipStream_t stream) {
    const float* x    = (const float*)d_in[0];
    const float* c1w  = (const float*)d_in[1];
    const float* c1b  = (const float*)d_in[2];
    const float* b1g  = (const float*)d_in[3];
    const float* b1b  = (const float*)d_in[4];
    const float* b1m  = (const float*)d_in[5];
    const float* b1v  = (const float*)d_in[6];
    const float* c2w  = (const float*)d_in[7];
    const float* c2b  = (const float*)d_in[8];
    const float* b2g  = (const float*)d_in[9];
    const float* b2b  = (const float*)d_in[10];
    const float* b2m  = (const float*)d_in[11];
    const float* b2v  = (const float*)d_in[12];
    const float* wih  = (const float*)d_in[13];
    const float* whh  = (const float*)d_in[14];
    const float* bih  = (const float*)d_in[15];
    const float* bhh  = (const float*)d_in[16];
    const float* rw1  = (const float*)d_in[17];
    const float* rb1  = (const float*)d_in[18];
    const float* rw2  = (const float*)d_in[19];
    const float* rb2  = (const float*)d_in[20];
    const float* fw   = (const float*)d_in[21];
    const float* fb   = (const float*)d_in[22];
    const float* cw1  = (const float*)d_in[23];
    const float* cb1  = (const float*)d_in[24];
    const float* cw2  = (const float*)d_in[25];
    const float* cb2  = (const float*)d_in[26];
    float* out = (float*)d_out;

    u64* spk  = (u64*)d_ws;                                            // 16.78 MB
    float* avg = (float*)((char*)d_ws + (size_t)32*NB*sizeof(u64));    // 3.15 MB

    k_conv_lif<<<dim3(NB/CBLK), dim3(CBLK), 0, stream>>>(x, c1w, c1b, b1g, b1b, b1m, b1v,
                                                         c2w, c2b, b2g, b2b, b2m, b2v, spk, avg);
    k_lstm_mfma<<<dim3(NB/64), dim3(256), 0, stream>>>(spk, avg, wih, whh, bih, bhh,
                                                       rw1, rb1, rw2, rb2, fw, fb,
                                                       cw1, cb1, cw2, cb2, out);
}

// Round 5
// 442.038 us; speedup vs baseline: 1.1756x; 1.0227x over previous
//
#include <hip/hip_runtime.h>

#define NB 65536
#define CBLK 256

typedef unsigned long long u64;
typedef __attribute__((ext_vector_type(8))) short short8;   // 8 bf16 (guide-verified typing)
typedef __attribute__((ext_vector_type(4))) float f32x4;

union FragAB { unsigned short us[8]; unsigned w[4]; short8 v; };

__device__ __forceinline__ float fast_rcp(float x){ return __builtin_amdgcn_rcpf(x); }
__device__ __forceinline__ float sigf(float x){ return fast_rcp(1.0f + __expf(-x)); }
__device__ __forceinline__ float tanh_fast(float x){ return 1.0f - 2.0f*fast_rcp(1.0f + __expf(2.0f*x)); }

__device__ __forceinline__ unsigned short f2bf(float f){
    union { float f; unsigned u; } x; x.f = f;
    unsigned r = x.u + 0x7FFFu + ((x.u >> 16) & 1u);   // RNE
    return (unsigned short)(r >> 16);
}
__device__ __forceinline__ float bf2f(unsigned short h){
    union { unsigned u; float f; } x; x.u = ((unsigned)h) << 16; return x.f;
}

// ============ Kernel 1: conv1+bn1+relu -> conv2+bn2+relu -> LIF1 -> LIF2 ============
// Round-1 structure restored (round-4 window double-buffer REVERTED: it raised VGPR
// 164->240 and dur 179->197). Only delta vs round 1: LIF membrane update written as
// selects (v1*1.0==v1, v1*0.0==0 -> bit-identical, fewer VALU ops).
__global__ __launch_bounds__(CBLK)
void k_conv_lif(const float* __restrict__ x,
                const float* __restrict__ c1w, const float* __restrict__ c1b,
                const float* __restrict__ b1g, const float* __restrict__ b1b,
                const float* __restrict__ b1m, const float* __restrict__ b1v,
                const float* __restrict__ c2w, const float* __restrict__ c2b,
                const float* __restrict__ b2g, const float* __restrict__ b2b,
                const float* __restrict__ b2m, const float* __restrict__ b2v,
                u64* __restrict__ spk,
                float* __restrict__ avg)
{
    const int b = blockIdx.x * CBLK + threadIdx.x;
    const float* xr = x + (size_t)b * 360;

    float w1f[6][5], c1f[6];
    #pragma unroll
    for (int c = 0; c < 6; ++c) {
        float s = b1g[c] / sqrtf(b1v[c] + 1e-5f);
        #pragma unroll
        for (int j = 0; j < 5; ++j) w1f[c][j] = c1w[c*5+j] * s;
        c1f[c] = (c1b[c] - b1m[c]) * s + b1b[c];
    }
    float s2v[12], t2v[12];
    #pragma unroll
    for (int c = 0; c < 12; ++c) {
        float s = b2g[c] / sqrtf(b2v[c] + 1e-5f);
        s2v[c] = s;
        t2v[c] = (c2b[c] - b2m[c]) * s + b2b[c];
    }

    float m1[33], m2[33];
    #pragma unroll
    for (int k = 0; k < 33; ++k) { m1[k] = 0.f; m2[k] = 0.f; }

    float sum12[12];
    #pragma unroll
    for (int c = 0; c < 12; ++c) sum12[c] = 0.f;

    float hA[6], hB[6], hC[6];
    #pragma unroll
    for (int c = 0; c < 6; ++c) hA[c] = 0.f;

    #pragma unroll 1
    for (int ss = 0; ss < 8; ++ss) {
        float xw[52];
        #pragma unroll
        for (int e = 0; e < 13; ++e) {
            int gi = 44*ss - 4 + 4*e;
            float4 v;
            if (gi >= 0) v = *(const float4*)(xr + gi);
            else         v = make_float4(0.f, 0.f, 0.f, 0.f);
            xw[4*e+0] = v.x; xw[4*e+1] = v.y; xw[4*e+2] = v.z; xw[4*e+3] = v.w;
        }

        unsigned curlo = 0u, curhi = 0u;
        #pragma unroll
        for (int pi = 0; pi < 11; ++pi) {
            const float xv0 = xw[4*pi+2], xv1 = xw[4*pi+3], xv2 = xw[4*pi+4],
                        xv3 = xw[4*pi+5], xv4 = xw[4*pi+6], xv5 = xw[4*pi+7],
                        xv6 = xw[4*pi+8];
            #pragma unroll
            for (int c = 0; c < 6; ++c) {
                float aB = c1f[c] + w1f[c][0]*xv0 + w1f[c][1]*xv1 + w1f[c][2]*xv2
                                  + w1f[c][3]*xv3 + w1f[c][4]*xv4;
                float aC = c1f[c] + w1f[c][0]*xv2 + w1f[c][1]*xv3 + w1f[c][2]*xv4
                                  + w1f[c][3]*xv5 + w1f[c][4]*xv6;
                hB[c] = fmaxf(aB, 0.f);
                hC[c] = fmaxf(aC, 0.f);
            }
            #pragma unroll
            for (int c2 = 0; c2 < 12; ++c2) {
                float acc = 0.f;
                #pragma unroll
                for (int c1 = 0; c1 < 6; ++c1) {
                    const float* wp = c2w + c2*18 + c1*3;
                    acc += wp[0]*hA[c1] + wp[1]*hB[c1] + wp[2]*hC[c1];
                }
                float hv = fmaxf(acc*s2v[c2] + t2v[c2], 0.f);
                sum12[c2] += hv;

                const int ls = 12*pi + c2;
                const int kk = ls % 33;
                float v1 = 0.95f*m1[kk] + hv;
                bool s1 = (v1 > 0.5f);
                m1[kk] = s1 ? 0.f : v1;                  // == v1*(1-sp1) bit-exactly
                float v2 = 0.9f*m2[kk] + (s1 ? 1.f : 0.f);
                bool sp2 = (v2 > 0.6f);
                m2[kk] = sp2 ? 0.f : v2;
                if (sp2) { if (kk < 32) curlo |= (1u << kk); else curhi |= 1u; }
                if (kk == 32) {
                    spk[(size_t)(4*ss + ls/33)*NB + b] = ((u64)curhi << 32) | (u64)curlo;
                    curlo = 0u; curhi = 0u;
                }
            }
            #pragma unroll
            for (int c = 0; c < 6; ++c) hA[c] = hC[c];
        }
    }

    {
        float xw2[13];
        float4 a0 = *(const float4*)(xr + 348);
        float4 a1 = *(const float4*)(xr + 352);
        float4 a2 = *(const float4*)(xr + 356);
        xw2[0]=a0.x; xw2[1]=a0.y; xw2[2]=a0.z; xw2[3]=a0.w;
        xw2[4]=a1.x; xw2[5]=a1.y; xw2[6]=a1.z; xw2[7]=a1.w;
        xw2[8]=a2.x; xw2[9]=a2.y; xw2[10]=a2.z; xw2[11]=a2.w;
        xw2[12]=0.f;
        #pragma unroll
        for (int pt = 0; pt < 2; ++pt) {
            const float xv0 = xw2[2+4*pt], xv1 = xw2[3+4*pt], xv2 = xw2[4+4*pt],
                        xv3 = xw2[5+4*pt], xv4 = xw2[6+4*pt], xv5 = xw2[7+4*pt],
                        xv6 = xw2[8+4*pt];
            #pragma unroll
            for (int c = 0; c < 6; ++c) {
                float aB = c1f[c] + w1f[c][0]*xv0 + w1f[c][1]*xv1 + w1f[c][2]*xv2
                                  + w1f[c][3]*xv3 + w1f[c][4]*xv4;
                float aC = c1f[c] + w1f[c][0]*xv2 + w1f[c][1]*xv3 + w1f[c][2]*xv4
                                  + w1f[c][3]*xv5 + w1f[c][4]*xv6;
                hB[c] = fmaxf(aB, 0.f);
                hC[c] = fmaxf(aC, 0.f);
            }
            #pragma unroll
            for (int c2 = 0; c2 < 12; ++c2) {
                float acc = 0.f;
                #pragma unroll
                for (int c1 = 0; c1 < 6; ++c1) {
                    const float* wp = c2w + c2*18 + c1*3;
                    acc += wp[0]*hA[c1] + wp[1]*hB[c1] + wp[2]*hC[c1];
                }
                sum12[c2] += fmaxf(acc*s2v[c2] + t2v[c2], 0.f);
            }
            #pragma unroll
            for (int c = 0; c < 6; ++c) hA[c] = hC[c];
        }
    }
    #pragma unroll
    for (int c = 0; c < 12; ++c) avg[(size_t)c*NB + b] = sum12[c] / 90.0f;
}

// ============ Kernel 2: MFMA LSTM (split-bf16) + heads — ZERO LDS ============
// Round-4 structure (post-timing-stable at (256,2)). Deltas: spike prefetch ring
// depth 2 (covers L2/HBM miss latency on the 512KB-strided spike stream that sits
// on the serial chain) and avg loads hoisted above the t-loop (latency hidden
// under the whole recurrence).
__global__ __launch_bounds__(256, 2)
void k_lstm_mfma(const u64* __restrict__ spk,
                 const float* __restrict__ avg,
                 const float* __restrict__ wih, const float* __restrict__ whh,
                 const float* __restrict__ bih, const float* __restrict__ bhh,
                 const float* __restrict__ rw1, const float* __restrict__ rb1,
                 const float* __restrict__ rw2, const float* __restrict__ rb2,
                 const float* __restrict__ fw,  const float* __restrict__ fb,
                 const float* __restrict__ cw1, const float* __restrict__ cb1,
                 const float* __restrict__ cw2, const float* __restrict__ cb2,
                 float* __restrict__ out)
{
    const int tid  = threadIdx.x;
    const int lane = tid & 63;
    const int wv   = __builtin_amdgcn_readfirstlane(tid >> 6);
    const int q    = lane >> 4;       // k-slice group (A and B) / row-quad (C)
    const int n16  = lane & 15;       // sample col (B/C) ; row-in-tile (A)
    const int sample = blockIdx.x * 64 + wv * 16 + n16;
    const int q8 = q * 8;

    // ---- load A fragments (weights), one-time ----
    short8 WihHi[6][2], WihLo[6], WhhHi[6], WhhLo[6];
    #pragma unroll
    for (int m = 0; m < 6; ++m) {
        const int rowA = 16*m + n16;           // A-layout: row = lane&15
        const int u    = rowA >> 2;
        const int gt   = rowA & 3;
        const float* wr = wih + (gt*24 + u)*33;
        FragAB fh, fl;
        #pragma unroll
        for (int j = 0; j < 8; ++j) {
            float v = wr[q8 + j];              // k = q*8+j, all < 32 valid
            unsigned short h = f2bf(v);
            fh.us[j] = h;
            fl.us[j] = f2bf(v - bf2f(h));
        }
        WihHi[m][0] = fh.v; WihLo[m] = fl.v;

        // 2nd Wih k-tile: k=32 spike bit + row bias split at k=33 (hi) / k=34 (lo)
        FragAB f1z;
        #pragma unroll
        for (int j = 0; j < 8; ++j) f1z.us[j] = 0;
        if (q == 0) {
            f1z.us[0] = f2bf(wr[32]);
            float bs = bih[gt*24 + u] + bhh[gt*24 + u];
            unsigned short bh = f2bf(bs);
            f1z.us[1] = bh;
            f1z.us[2] = f2bf(bs - bf2f(bh));
        }
        WihHi[m][1] = f1z.v;

        // Whh A-fragment: k-slot s = 8q+j holds column for unit 4j+q (j<6), 0 for j=6,7
        const float* hr = whh + (gt*24 + u)*24;
        FragAB gh, gl;
        #pragma unroll
        for (int j = 0; j < 8; ++j) {
            float v = (j < 6) ? hr[4*j + q] : 0.f;
            unsigned short h = f2bf(v);
            gh.us[j] = (j < 6) ? h : (unsigned short)0;
            gl.us[j] = (j < 6) ? f2bf(v - bf2f(h)) : (unsigned short)0;
        }
        WhhHi[m] = gh.v; WhhLo[m] = gl.v;
    }

    // avg loads hoisted: values only needed in the head; latency hides under t-loop
    float av3[3];
    #pragma unroll
    for (int i = 0; i < 3; ++i) av3[i] = avg[(size_t)(3*q + i)*NB + sample];

    float cst[6], hreg[6];
    #pragma unroll
    for (int m = 0; m < 6; ++m) { cst[m] = 0.f; hreg[m] = 0.f; }

    // spike prefetch ring, depth 2
    const u64* sp = spk + sample;
    u64 w0 = sp[0];
    u64 w1 = sp[(size_t)1*NB];

    #pragma unroll 1
    for (int t = 0; t < 32; ++t) {
        const u64 wcur = w0;

        // prefetch t+2 early (ring)
        u64 w2 = 0;
        if (t < 30) w2 = sp[(size_t)(t+2)*NB];

        // B fragments for h(t-1): built from THIS lane's hreg (zeros at t=0).
        // hi = truncated top-16 bits, lo = RNE(residual)
        FragAB BH, BL;
        {
            union { float f; unsigned u; } hu[6];
            #pragma unroll
            for (int m = 0; m < 6; ++m) hu[m].f = hreg[m];
            #pragma unroll
            for (int jp = 0; jp < 3; ++jp) {
                unsigned u0 = hu[2*jp].u, u1 = hu[2*jp+1].u;
                BH.w[jp] = (u0 >> 16) | (u1 & 0xFFFF0000u);
                union { unsigned u; float f; } t0, t1;
                t0.u = u0 & 0xFFFF0000u; t1.u = u1 & 0xFFFF0000u;
                BL.w[jp] = (unsigned)f2bf(hu[2*jp].f - t0.f)
                         | ((unsigned)f2bf(hu[2*jp+1].f - t1.f) << 16);
            }
            BH.w[3] = 0u; BL.w[3] = 0u;
        }

        // B fragments for spikes (exact bf16 0/1)
        const unsigned lo32 = (unsigned)wcur;
        const unsigned hi32 = (unsigned)(wcur >> 32);
        FragAB bs0;
        {
            const unsigned byt = (lo32 >> q8) & 0xFFu;
            #pragma unroll
            for (int p = 0; p < 4; ++p) {
                unsigned e0 = (byt >> (2*p)) & 1u;
                unsigned e1 = (byt >> (2*p+1)) & 1u;
                bs0.w[p] = (e0 ? 0x3F80u : 0u) | (e1 ? 0x3F800000u : 0u);
            }
        }
        // k=32 spike + constant 1.0 at k=33/34 (bias slots); q!=0 lanes' extras hit A-zeros
        FragAB bs1;
        bs1.w[0] = 0x3F800000u | ((hi32 & 1u) ? 0x3F80u : 0u);
        bs1.w[1] = 0x00003F80u;
        bs1.w[2] = 0u; bs1.w[3] = 0u;

        // gates = (bias via k33/34) + Wih*spk + Whh*h  (split-bf16)
        f32x4 acc[6];
        #pragma unroll
        for (int m = 0; m < 6; ++m) {
            f32x4 a = {0.f, 0.f, 0.f, 0.f};
            a = __builtin_amdgcn_mfma_f32_16x16x32_bf16(WihHi[m][0], bs0.v, a, 0, 0, 0);
            a = __builtin_amdgcn_mfma_f32_16x16x32_bf16(WihLo[m],    bs0.v, a, 0, 0, 0);
            a = __builtin_amdgcn_mfma_f32_16x16x32_bf16(WihHi[m][1], bs1.v, a, 0, 0, 0);
            a = __builtin_amdgcn_mfma_f32_16x16x32_bf16(WhhHi[m],    BH.v,  a, 0, 0, 0);
            a = __builtin_amdgcn_mfma_f32_16x16x32_bf16(WhhLo[m],    BH.v,  a, 0, 0, 0);
            a = __builtin_amdgcn_mfma_f32_16x16x32_bf16(WhhHi[m],    BL.v,  a, 0, 0, 0);
            acc[m] = a;
        }

        // epilogue: lane-local LSTM cell for units 4m+q of its sample
        #pragma unroll
        for (int m = 0; m < 6; ++m) {
            float ii = sigf(acc[m][0]);
            float ff = sigf(acc[m][1]);
            float gg = tanh_fast(acc[m][2]);
            float oo = sigf(acc[m][3]);
            float cn = ff*cst[m] + ii*gg;
            cst[m] = cn;
            hreg[m] = oo * tanh_fast(cn);
        }
        w0 = w1;
        w1 = w2;
    }

    // ---------- head: all 64 lanes, 4 lanes per sample, shfl_xor(16/32) butterflies ----------
    float f1v[12];
    #pragma unroll
    for (int r = 0; r < 12; ++r) {
        float a = 0.f;
        #pragma unroll
        for (int m = 0; m < 6; ++m) a += rw1[r*36 + 4*m + q] * hreg[m];
        #pragma unroll
        for (int i = 0; i < 3; ++i) a += rw1[r*36 + 24 + 3*q + i] * av3[i];
        a += __shfl_xor(a, 16);
        a += __shfl_xor(a, 32);
        f1v[r] = fmaxf(a + rb1[r], 0.f);
    }
    float z0 = rb2[0], z1 = rb2[1];
    #pragma unroll
    for (int r = 0; r < 12; ++r) { z0 += rw2[r]*f1v[r]; z1 += rw2[12+r]*f1v[r]; }
    float mz = fmaxf(z0, z1);
    float e0 = 0.7f*__expf(z0 - mz), e1 = 0.3f*__expf(z1 - mz);
    float alpha = e0 * fast_rcp(e0 + e1);

    float ha[6], sa3[3];
    #pragma unroll
    for (int m = 0; m < 6; ++m) ha[m] = hreg[m]*alpha;
    #pragma unroll
    for (int i = 0; i < 3; ++i) sa3[i] = av3[i]*(1.f - alpha);

    float fuv[24];
    #pragma unroll
    for (int r = 0; r < 24; ++r) {
        float a = 0.f;
        #pragma unroll
        for (int m = 0; m < 6; ++m) a += fw[r*36 + 4*m + q] * ha[m];
        #pragma unroll
        for (int i = 0; i < 3; ++i) a += fw[r*36 + 24 + 3*q + i] * sa3[i];
        a += __shfl_xor(a, 16);
        a += __shfl_xor(a, 32);
        fuv[r] = fmaxf(a + fb[r], 0.f);
    }
    // classifier layer 1: lane q owns rows 3q..3q+2 (static register indexing only)
    float c1r[3];
    #pragma unroll
    for (int k = 0; k < 3; ++k) {
        const int r = 3*q + k;
        float a = cb1[r];
        #pragma unroll
        for (int u2 = 0; u2 < 24; ++u2) a += cw1[r*24 + u2] * fuv[u2];
        c1r[k] = fmaxf(a, 0.f);
    }
    // output layer: butterfly partial sums over the distributed c1 rows
    #pragma unroll
    for (int o = 0; o < 5; ++o) {
        float a = 0.f;
        #pragma unroll
        for (int k = 0; k < 3; ++k) a += cw2[o*12 + 3*q + k] * c1r[k];
        a += __shfl_xor(a, 16);
        a += __shfl_xor(a, 32);
        if (q == 0) out[(size_t)sample*5 + o] = a + cb2[o];
    }
}

extern "C" void kernel_launch(void* const* d_in, const int* in_sizes, int n_in,
                              void* d_out, int out_size, void* d_ws, size_t ws_size,
                              hipStream_t stream) {
    const float* x    = (const float*)d_in[0];
    const float* c1w  = (const float*)d_in[1];
    const float* c1b  = (const float*)d_in[2];
    const float* b1g  = (const float*)d_in[3];
    const float* b1b  = (const float*)d_in[4];
    const float* b1m  = (const float*)d_in[5];
    const float* b1v  = (const float*)d_in[6];
    const float* c2w  = (const float*)d_in[7];
    const float* c2b  = (const float*)d_in[8];
    const float* b2g  = (const float*)d_in[9];
    const float* b2b  = (const float*)d_in[10];
    const float* b2m  = (const float*)d_in[11];
    const float* b2v  = (const float*)d_in[12];
    const float* wih  = (const float*)d_in[13];
    const float* whh  = (const float*)d_in[14];
    const float* bih  = (const float*)d_in[15];
    const float* bhh  = (const float*)d_in[16];
    const float* rw1  = (const float*)d_in[17];
    const float* rb1  = (const float*)d_in[18];
    const float* rw2  = (const float*)d_in[19];
    const float* rb2  = (const float*)d_in[20];
    const float* fw   = (const float*)d_in[21];
    const float* fb   = (const float*)d_in[22];
    const float* cw1  = (const float*)d_in[23];
    const float* cb1  = (const float*)d_in[24];
    const float* cw2  = (const float*)d_in[25];
    const float* cb2  = (const float*)d_in[26];
    float* out = (float*)d_out;

    u64* spk  = (u64*)d_ws;                                            // 16.78 MB
    float* avg = (float*)((char*)d_ws + (size_t)32*NB*sizeof(u64));    // 3.15 MB

    k_conv_lif<<<dim3(NB/CBLK), dim3(CBLK), 0, stream>>>(x, c1w, c1b, b1g, b1b, b1m, b1v,
                                                         c2w, c2b, b2g, b2b, b2m, b2v, spk, avg);
    k_lstm_mfma<<<dim3(NB/64), dim3(256), 0, stream>>>(spk, avg, wih, whh, bih, bhh,
                                                       rw1, rb1, rw2, rb2, fw, fb,
                                                       cw1, cb1, cw2, cb2, out);
}